// Round 5
// baseline (153.319 us; speedup 1.0000x reference)
//
#include <hip/hip_runtime.h>
#include <math.h>

static constexpr int B_ = 32, M_ = 100, L_ = 30, LQ_ = 30, E_ = 256, V_ = 32000;

// ---------------- Kernel 1: story embeddings, E-sliced + XCD-pinned.
// combo c=(t,s): blk = s + 8*(t*100+i) -> XCD = blk%8 = s; within an XCD, t serializes.
// Per-XCD working set = one 4MB table-slice => duplicate row reads hit L2.
// Block: 256 thr = 4 waves; wave = 8 (b,m) groups x 8 lanes; lane covers 4 floats of slice s.
__global__ __launch_bounds__(256) void k_embed(const int* __restrict__ trainS,
                                               const float* __restrict__ A1,
                                               const float* __restrict__ A2,
                                               const float* __restrict__ A3,
                                               const float* __restrict__ A4,
                                               float* __restrict__ embA) {
    const int blk = blockIdx.x;
    const int s = blk & 7;          // e-slice (and intended XCD)
    const int q = blk >> 3;
    const int t = q / 100;          // table
    const int i = q % 100;          // bm-chunk
    const int tid = threadIdx.x;
    const int w = tid >> 6;
    const int lane = tid & 63;
    const int g = lane >> 3;        // bm group within wave
    const int sub = lane & 7;       // float4 slot within 32-float slice

    const float* __restrict__ At = (t == 0) ? A1 : (t == 1) ? A2 : (t == 2) ? A3 : A4;

    __shared__ int sidx[32 * L_];   // 960 indices for this chunk's 32 (b,m)
    for (int j = tid; j < 240; j += 256)
        reinterpret_cast<int4*>(sidx)[j] = reinterpret_cast<const int4*>(trainS + i * 960)[j];
    __syncthreads();

    const int bm = i * 32 + w * 8 + g;
    const int eoff = s * 32 + sub * 4;
    const float half_e = (E_ + 1) * 0.5f;
    const float half_j = (L_ + 1) * 0.5f;
    const float inv = 1.0f / (float)(E_ * L_);
    const float k0 = (float)(eoff + 1) - half_e;
    const float k1 = k0 + 1.f, k2 = k0 + 2.f, k3 = k0 + 3.f;
    const int lbase = (w * 8 + g) * L_;

    float4 acc = make_float4(0.f, 0.f, 0.f, 0.f);
#pragma unroll
    for (int c = 0; c < 3; ++c) {
        int id[10];
#pragma unroll
        for (int j = 0; j < 10; ++j) id[j] = sidx[lbase + c * 10 + j];
        float4 r[10];
#pragma unroll
        for (int j = 0; j < 10; ++j)
            r[j] = *reinterpret_cast<const float4*>(At + (size_t)id[j] * E_ + eoff);
        __builtin_amdgcn_sched_barrier(0);
#pragma unroll
        for (int j = 0; j < 10; ++j) {
            const int l = c * 10 + j;
            const float coef = 4.0f * ((float)(l + 1) - half_j) * inv;
            acc.x += r[j].x * (1.0f + coef * k0);
            acc.y += r[j].y * (1.0f + coef * k1);
            acc.z += r[j].z * (1.0f + coef * k2);
            acc.w += r[j].w * (1.0f + coef * k3);
        }
    }
    *reinterpret_cast<float4*>(embA + (size_t)t * (B_ * M_ * E_) + (size_t)bm * E_ + eoff) = acc;
}

// ---------------- Kernel 2: query embedding + three attention hops. One 1024-thread block per b.
// Also zeroes partial[b] for k_output's atomics. Output u written TRANSPOSED u_T[e*B+b].
__global__ __launch_bounds__(1024) void k_hops(const int* __restrict__ trainQ,
                                               const float* __restrict__ trainQM,
                                               const float* __restrict__ A1,
                                               const float* __restrict__ embA,
                                               const float* __restrict__ trainPM,
                                               float* __restrict__ u_T,
                                               float* __restrict__ partial) {
    const int b = blockIdx.x;
    const int tid = threadIdx.x;
    const int lane = tid & 63;
    const int wave = tid >> 6;
    const int g = tid >> 8;
    const int e = tid & 255;
    if (tid == 0) partial[b] = 0.f;
    __shared__ float u_sh[E_];
    __shared__ float sc[M_];
    __shared__ float p_sh[M_];
    __shared__ float osum[4][E_];

    {
        const float half_e = (E_ + 1) * 0.5f;
        const float half_j = (LQ_ + 1) * 0.5f;
        const float inv = 1.0f / (float)(E_ * LQ_);
        const float ke = (float)(e + 1) - half_e;
        const int l0 = g * 8;
        const int ln = (LQ_ - l0 < 8) ? (LQ_ - l0) : 8;
        int qi[8];
        float qm[8];
#pragma unroll
        for (int j = 0; j < 8; ++j) {
            if (j < ln) {
                qi[j] = trainQ[b * LQ_ + l0 + j];
                qm[j] = trainQM[b * LQ_ + l0 + j];
            } else { qi[j] = 0; qm[j] = 0.f; }
        }
        float r[8];
#pragma unroll
        for (int j = 0; j < 8; ++j)
            r[j] = (j < ln) ? A1[(size_t)qi[j] * E_ + e] : 0.f;
        float part = 0.f;
#pragma unroll
        for (int j = 0; j < 8; ++j) {
            const float pe = 1.0f + 4.0f * ke * ((float)(l0 + j + 1) - half_j) * inv;
            part += r[j] * pe * qm[j];
        }
        osum[g][e] = part;
    }
    __syncthreads();
    if (tid < E_) u_sh[tid] = osum[0][tid] + osum[1][tid] + osum[2][tid] + osum[3][tid];
    __syncthreads();

    for (int hop = 0; hop < 3; ++hop) {
        const float* memA = embA + (size_t)hop * (B_ * M_ * E_) + (size_t)b * M_ * E_;
        const float* memC = memA + (size_t)(B_ * M_ * E_);
#pragma unroll 2
        for (int m = wave; m < M_; m += 16) {
            const float* row = memA + m * E_;
            float part = 0.f;
#pragma unroll
            for (int j = 0; j < 4; ++j)
                part += row[lane + 64 * j] * u_sh[lane + 64 * j];
#pragma unroll
            for (int off = 32; off > 0; off >>= 1)
                part += __shfl_xor(part, off, 64);
            if (lane == 0) sc[m] = part * trainPM[b * M_ + m];
        }
        __syncthreads();
        if (wave == 0) {
            const float pm0 = (lane < M_) ? trainPM[b * M_ + lane] : 0.f;
            const float pm1 = (lane + 64 < M_) ? trainPM[b * M_ + lane + 64] : 0.f;
            const float x0 = (lane < M_ && pm0 > 0.f) ? sc[lane] : -1e30f;
            const float x1 = (lane + 64 < M_ && pm1 > 0.f) ? sc[lane + 64] : -1e30f;
            float mx = fmaxf(x0, x1);
#pragma unroll
            for (int off = 32; off > 0; off >>= 1)
                mx = fmaxf(mx, __shfl_xor(mx, off, 64));
            const float e0v = (lane < M_) ? expf(x0 - mx) * pm0 : 0.f;
            const float e1v = (lane + 64 < M_) ? expf(x1 - mx) * pm1 : 0.f;
            float ssum = e0v + e1v;
#pragma unroll
            for (int off = 32; off > 0; off >>= 1)
                ssum += __shfl_xor(ssum, off, 64);
            const float invs = 1.0f / (ssum + 1e-13f);
            if (lane < M_) p_sh[lane] = e0v * invs;
            if (lane + 64 < M_) p_sh[lane + 64] = e1v * invs;
        }
        __syncthreads();
        {
            float acc = 0.f;
            const float* crow = memC + e;
            const int m0 = g * 25;
#pragma unroll 5
            for (int mm = 0; mm < 25; ++mm)
                acc += p_sh[m0 + mm] * crow[(size_t)(m0 + mm) * E_];
            osum[g][e] = acc;
        }
        __syncthreads();
        if (tid < E_) u_sh[tid] += osum[0][tid] + osum[1][tid] + osum[2][tid] + osum[3][tid];
        __syncthreads();
    }
    if (tid < E_) u_T[tid * B_ + b] = u_sh[tid];
}

// ---------------- Kernel 3: wx = u @ W.T + b; batch-LN; z = y + log(VM); exp-partials via atomics.
__global__ __launch_bounds__(256) void k_output(const float* __restrict__ u_T,
                                                const float* __restrict__ Wm,
                                                const float* __restrict__ bias,
                                                const float* __restrict__ gamma,
                                                const float* __restrict__ beta,
                                                const float* __restrict__ VM,
                                                float* __restrict__ z,
                                                float* __restrict__ partial) {
    __shared__ float u_lds[E_ * B_];
    __shared__ float pex[B_];
    const int tid = threadIdx.x;
    for (int i = tid; i < (E_ * B_) / 4; i += 256)
        reinterpret_cast<float4*>(u_lds)[i] = reinterpret_cast<const float4*>(u_T)[i];
    if (tid < B_) pex[tid] = 0.f;
    __syncthreads();

    const int bg = tid & 7;
    const int vl = tid >> 3;
    const int v0 = blockIdx.x * 64 + vl * 2;
    const int v1 = v0 + 1;
    const float* __restrict__ wr0 = Wm + (size_t)v0 * E_;
    const float* __restrict__ wr1 = Wm + (size_t)v1 * E_;

    float accA[4] = {0.f, 0.f, 0.f, 0.f};
    float accB[4] = {0.f, 0.f, 0.f, 0.f};

#pragma unroll
    for (int c = 0; c < 8; ++c) {
        float4 wa[8], wb[8];
#pragma unroll
        for (int j = 0; j < 8; ++j) {
            wa[j] = reinterpret_cast<const float4*>(wr0)[c * 8 + j];
            wb[j] = reinterpret_cast<const float4*>(wr1)[c * 8 + j];
        }
        __builtin_amdgcn_sched_barrier(0);
#pragma unroll
        for (int j = 0; j < 8; ++j) {
#pragma unroll
            for (int eo = 0; eo < 4; ++eo) {
                const int e = c * 32 + j * 4 + eo;
                const float4 u4 = *reinterpret_cast<const float4*>(u_lds + e * B_ + bg * 4);
                const float w0 = (eo == 0) ? wa[j].x : (eo == 1) ? wa[j].y : (eo == 2) ? wa[j].z : wa[j].w;
                const float w1 = (eo == 0) ? wb[j].x : (eo == 1) ? wb[j].y : (eo == 2) ? wb[j].z : wb[j].w;
                accA[0] += w0 * u4.x; accA[1] += w0 * u4.y; accA[2] += w0 * u4.z; accA[3] += w0 * u4.w;
                accB[0] += w1 * u4.x; accB[1] += w1 * u4.y; accB[2] += w1 * u4.z; accB[3] += w1 * u4.w;
            }
        }
    }

    const float bvA = bias[v0], bvB = bias[v1];
    float s1a = 0.f, s2a = 0.f, s1b = 0.f, s2b = 0.f;
#pragma unroll
    for (int i = 0; i < 4; ++i) {
        accA[i] += bvA; accB[i] += bvB;
        s1a += accA[i]; s2a += accA[i] * accA[i];
        s1b += accB[i]; s2b += accB[i] * accB[i];
    }
#pragma unroll
    for (int off = 1; off < 8; off <<= 1) {
        s1a += __shfl_xor(s1a, off, 64);
        s2a += __shfl_xor(s2a, off, 64);
        s1b += __shfl_xor(s1b, off, 64);
        s2b += __shfl_xor(s2b, off, 64);
    }
    const float meanA = s1a * (1.0f / B_);
    const float meanB = s1b * (1.0f / B_);
    const float varA = s2a * (1.0f / B_) - meanA * meanA;
    const float varB = s2b * (1.0f / B_) - meanB * meanB;
    const float rstdA = rsqrtf(varA + 1e-5f);
    const float rstdB = rsqrtf(varB + 1e-5f);
    const float gA = gamma[v0], beA = beta[v0];
    const float gB = gamma[v1], beB = beta[v1];

    float exs[4];
#pragma unroll
    for (int i = 0; i < 4; ++i) {
        const int b = bg * 4 + i;
        const size_t row = (size_t)b * V_;
        const float vm0 = VM[row + v0] + 1e-13f;
        const float vm1 = VM[row + v1] + 1e-13f;
        const float y0 = gA * (accA[i] - meanA) * rstdA + beA;
        const float y1 = gB * (accB[i] - meanB) * rstdB + beB;
        z[row + v0] = y0 + logf(vm0);
        z[row + v1] = y1 + logf(vm1);
        exs[i] = vm0 * expf(y0) + vm1 * expf(y1);
    }
#pragma unroll
    for (int i = 0; i < 4; ++i)
        atomicAdd(&pex[bg * 4 + i], exs[i]);
    __syncthreads();
    if (tid < B_) atomicAdd(&partial[tid], pex[tid]);
}

// ---------------- Kernel 4: out = z - log(partial[b])
__global__ __launch_bounds__(256) void k_final(const float* __restrict__ z,
                                               const float* __restrict__ partial,
                                               float* __restrict__ out) {
    const int idx = blockIdx.x * 256 + threadIdx.x;
    const int b = idx / (V_ / 4);
    const int v4 = idx % (V_ / 4);
    const float lse = logf(partial[b]);
    const float4 x = reinterpret_cast<const float4*>(z + (size_t)b * V_)[v4];
    float4 o;
    o.x = x.x - lse; o.y = x.y - lse; o.z = x.z - lse; o.w = x.w - lse;
    reinterpret_cast<float4*>(out + (size_t)b * V_)[v4] = o;
}

extern "C" void kernel_launch(void* const* d_in, const int* in_sizes, int n_in,
                              void* d_out, int out_size, void* d_ws, size_t ws_size,
                              hipStream_t stream) {
    const int* trainS = (const int*)d_in[0];
    const int* trainQ = (const int*)d_in[1];
    const float* trainVM = (const float*)d_in[2];
    const float* trainPM = (const float*)d_in[3];
    const float* trainQM = (const float*)d_in[5];
    const float* A1 = (const float*)d_in[6];
    const float* A2 = (const float*)d_in[7];
    const float* A3 = (const float*)d_in[8];
    const float* A4 = (const float*)d_in[9];
    const float* Wm = (const float*)d_in[10];
    const float* bias = (const float*)d_in[11];
    const float* gamma = (const float*)d_in[12];
    const float* beta = (const float*)d_in[13];
    float* out = (float*)d_out;

    float* ws = (float*)d_ws;
    float* u_T = ws;                                 // E*B = 8192 (transposed)
    float* embA = ws + 8192;                         // 4*B*M*E = 3,276,800
    float* z = embA + 4 * (B_ * M_ * E_);            // B*V = 1,024,000
    float* partial = z + (size_t)B_ * V_;            // 32

    k_embed<<<B_ * M_ * 4, 256, 0, stream>>>(trainS, A1, A2, A3, A4, embA);
    k_hops<<<B_, 1024, 0, stream>>>(trainQ, trainQM, A1, embA, trainPM, u_T, partial);
    k_output<<<V_ / 64, 256, 0, stream>>>(u_T, Wm, bias, gamma, beta, trainVM, z, partial);
    k_final<<<(B_ * V_ / 4) / 256, 256, 0, stream>>>(z, partial, out);
}

// Round 6
// 106.981 us; speedup vs baseline: 1.4331x; 1.4331x over previous
//
#include <hip/hip_runtime.h>
#include <math.h>

static constexpr int B_ = 32, M_ = 100, L_ = 30, LQ_ = 30, E_ = 256, V_ = 32000;

// ---------------- Kernel 1: story embeddings embA_k[b,m,:] = sum_l A_k[S[b,m,l]] * pe_s[l,:]
// R1 structure (known 66us = L2-fill wall for 393MB of random 1KB row gathers).
// One block per (b,m); wave w = table w; 64 lanes x float4 = one contiguous 1KB row per gather.
__global__ __launch_bounds__(256) void k_embed(const int* __restrict__ trainS,
                                               const float* __restrict__ A1,
                                               const float* __restrict__ A2,
                                               const float* __restrict__ A3,
                                               const float* __restrict__ A4,
                                               float* __restrict__ embA) {
    const int bm = blockIdx.x;
    const int tbl = threadIdx.x >> 6;
    const int e0 = (threadIdx.x & 63) * 4;
    const float* __restrict__ A = (tbl == 0) ? A1 : (tbl == 1) ? A2 : (tbl == 2) ? A3 : A4;
    const float half_e = (E_ + 1) * 0.5f;
    const float half_j = (L_ + 1) * 0.5f;
    const float inv = 1.0f / (float)(E_ * L_);
    const float k0 = (float)(e0 + 1) - half_e;
    const float k1 = k0 + 1.f, k2 = k0 + 2.f, k3 = k0 + 3.f;

    int idx[L_];
#pragma unroll
    for (int l = 0; l < L_; ++l) idx[l] = trainS[bm * L_ + l];  // uniform -> s_load

    float4 acc = make_float4(0.f, 0.f, 0.f, 0.f);
#pragma unroll
    for (int c = 0; c < 2; ++c) {
        float4 r[15];
#pragma unroll
        for (int j = 0; j < 15; ++j)
            r[j] = *reinterpret_cast<const float4*>(A + (size_t)idx[c * 15 + j] * E_ + e0);
        __builtin_amdgcn_sched_barrier(0);
#pragma unroll
        for (int j = 0; j < 15; ++j) {
            const int l = c * 15 + j;
            const float coef = 4.0f * ((float)(l + 1) - half_j) * inv;
            acc.x += r[j].x * (1.0f + coef * k0);
            acc.y += r[j].y * (1.0f + coef * k1);
            acc.z += r[j].z * (1.0f + coef * k2);
            acc.w += r[j].w * (1.0f + coef * k3);
        }
    }
    *reinterpret_cast<float4*>(embA + (size_t)tbl * (B_ * M_ * E_) + (size_t)bm * E_ + e0) = acc;
}

// ---------------- Kernel 2: query embedding + three attention hops. One 1024-thread block per b.
// Also zeroes partial[b] for k_output's atomics. Output u written TRANSPOSED u_T[e*B+b].
__global__ __launch_bounds__(1024) void k_hops(const int* __restrict__ trainQ,
                                               const float* __restrict__ trainQM,
                                               const float* __restrict__ A1,
                                               const float* __restrict__ embA,
                                               const float* __restrict__ trainPM,
                                               float* __restrict__ u_T,
                                               float* __restrict__ partial) {
    const int b = blockIdx.x;
    const int tid = threadIdx.x;
    const int lane = tid & 63;
    const int wave = tid >> 6;
    const int g = tid >> 8;
    const int e = tid & 255;
    if (tid == 0) partial[b] = 0.f;
    __shared__ float u_sh[E_];
    __shared__ float sc[M_];
    __shared__ float p_sh[M_];
    __shared__ float osum[4][E_];

    {
        const float half_e = (E_ + 1) * 0.5f;
        const float half_j = (LQ_ + 1) * 0.5f;
        const float inv = 1.0f / (float)(E_ * LQ_);
        const float ke = (float)(e + 1) - half_e;
        const int l0 = g * 8;
        const int ln = (LQ_ - l0 < 8) ? (LQ_ - l0) : 8;
        int qi[8];
        float qm[8];
#pragma unroll
        for (int j = 0; j < 8; ++j) {
            if (j < ln) {
                qi[j] = trainQ[b * LQ_ + l0 + j];
                qm[j] = trainQM[b * LQ_ + l0 + j];
            } else { qi[j] = 0; qm[j] = 0.f; }
        }
        float r[8];
#pragma unroll
        for (int j = 0; j < 8; ++j)
            r[j] = (j < ln) ? A1[(size_t)qi[j] * E_ + e] : 0.f;
        float part = 0.f;
#pragma unroll
        for (int j = 0; j < 8; ++j) {
            const float pe = 1.0f + 4.0f * ke * ((float)(l0 + j + 1) - half_j) * inv;
            part += r[j] * pe * qm[j];
        }
        osum[g][e] = part;
    }
    __syncthreads();
    if (tid < E_) u_sh[tid] = osum[0][tid] + osum[1][tid] + osum[2][tid] + osum[3][tid];
    __syncthreads();

    for (int hop = 0; hop < 3; ++hop) {
        const float* memA = embA + (size_t)hop * (B_ * M_ * E_) + (size_t)b * M_ * E_;
        const float* memC = memA + (size_t)(B_ * M_ * E_);
#pragma unroll 2
        for (int m = wave; m < M_; m += 16) {
            const float* row = memA + m * E_;
            float part = 0.f;
#pragma unroll
            for (int j = 0; j < 4; ++j)
                part += row[lane + 64 * j] * u_sh[lane + 64 * j];
#pragma unroll
            for (int off = 32; off > 0; off >>= 1)
                part += __shfl_xor(part, off, 64);
            if (lane == 0) sc[m] = part * trainPM[b * M_ + m];
        }
        __syncthreads();
        if (wave == 0) {
            const float pm0 = (lane < M_) ? trainPM[b * M_ + lane] : 0.f;
            const float pm1 = (lane + 64 < M_) ? trainPM[b * M_ + lane + 64] : 0.f;
            const float x0 = (lane < M_ && pm0 > 0.f) ? sc[lane] : -1e30f;
            const float x1 = (lane + 64 < M_ && pm1 > 0.f) ? sc[lane + 64] : -1e30f;
            float mx = fmaxf(x0, x1);
#pragma unroll
            for (int off = 32; off > 0; off >>= 1)
                mx = fmaxf(mx, __shfl_xor(mx, off, 64));
            const float e0v = (lane < M_) ? expf(x0 - mx) * pm0 : 0.f;
            const float e1v = (lane + 64 < M_) ? expf(x1 - mx) * pm1 : 0.f;
            float ssum = e0v + e1v;
#pragma unroll
            for (int off = 32; off > 0; off >>= 1)
                ssum += __shfl_xor(ssum, off, 64);
            const float invs = 1.0f / (ssum + 1e-13f);
            if (lane < M_) p_sh[lane] = e0v * invs;
            if (lane + 64 < M_) p_sh[lane + 64] = e1v * invs;
        }
        __syncthreads();
        {
            float acc = 0.f;
            const float* crow = memC + e;
            const int m0 = g * 25;
#pragma unroll 5
            for (int mm = 0; mm < 25; ++mm)
                acc += p_sh[m0 + mm] * crow[(size_t)(m0 + mm) * E_];
            osum[g][e] = acc;
        }
        __syncthreads();
        if (tid < E_) u_sh[tid] += osum[0][tid] + osum[1][tid] + osum[2][tid] + osum[3][tid];
        __syncthreads();
    }
    if (tid < E_) u_T[tid * B_ + b] = u_sh[tid];
}

// ---------------- Kernel 3: wx = u @ W.T + b; batch-LN; z = y + log(VM); exp-partials via atomics.
__global__ __launch_bounds__(256) void k_output(const float* __restrict__ u_T,
                                                const float* __restrict__ Wm,
                                                const float* __restrict__ bias,
                                                const float* __restrict__ gamma,
                                                const float* __restrict__ beta,
                                                const float* __restrict__ VM,
                                                float* __restrict__ z,
                                                float* __restrict__ partial) {
    __shared__ float u_lds[E_ * B_];
    __shared__ float pex[B_];
    const int tid = threadIdx.x;
    for (int i = tid; i < (E_ * B_) / 4; i += 256)
        reinterpret_cast<float4*>(u_lds)[i] = reinterpret_cast<const float4*>(u_T)[i];
    if (tid < B_) pex[tid] = 0.f;
    __syncthreads();

    const int bg = tid & 7;
    const int vl = tid >> 3;
    const int v0 = blockIdx.x * 64 + vl * 2;
    const int v1 = v0 + 1;
    const float* __restrict__ wr0 = Wm + (size_t)v0 * E_;
    const float* __restrict__ wr1 = Wm + (size_t)v1 * E_;

    float accA[4] = {0.f, 0.f, 0.f, 0.f};
    float accB[4] = {0.f, 0.f, 0.f, 0.f};

#pragma unroll
    for (int c = 0; c < 8; ++c) {
        float4 wa[8], wb[8];
#pragma unroll
        for (int j = 0; j < 8; ++j) {
            wa[j] = reinterpret_cast<const float4*>(wr0)[c * 8 + j];
            wb[j] = reinterpret_cast<const float4*>(wr1)[c * 8 + j];
        }
        __builtin_amdgcn_sched_barrier(0);
#pragma unroll
        for (int j = 0; j < 8; ++j) {
#pragma unroll
            for (int eo = 0; eo < 4; ++eo) {
                const int e = c * 32 + j * 4 + eo;
                const float4 u4 = *reinterpret_cast<const float4*>(u_lds + e * B_ + bg * 4);
                const float w0 = (eo == 0) ? wa[j].x : (eo == 1) ? wa[j].y : (eo == 2) ? wa[j].z : wa[j].w;
                const float w1 = (eo == 0) ? wb[j].x : (eo == 1) ? wb[j].y : (eo == 2) ? wb[j].z : wb[j].w;
                accA[0] += w0 * u4.x; accA[1] += w0 * u4.y; accA[2] += w0 * u4.z; accA[3] += w0 * u4.w;
                accB[0] += w1 * u4.x; accB[1] += w1 * u4.y; accB[2] += w1 * u4.z; accB[3] += w1 * u4.w;
            }
        }
    }

    const float bvA = bias[v0], bvB = bias[v1];
    float s1a = 0.f, s2a = 0.f, s1b = 0.f, s2b = 0.f;
#pragma unroll
    for (int i = 0; i < 4; ++i) {
        accA[i] += bvA; accB[i] += bvB;
        s1a += accA[i]; s2a += accA[i] * accA[i];
        s1b += accB[i]; s2b += accB[i] * accB[i];
    }
#pragma unroll
    for (int off = 1; off < 8; off <<= 1) {
        s1a += __shfl_xor(s1a, off, 64);
        s2a += __shfl_xor(s2a, off, 64);
        s1b += __shfl_xor(s1b, off, 64);
        s2b += __shfl_xor(s2b, off, 64);
    }
    const float meanA = s1a * (1.0f / B_);
    const float meanB = s1b * (1.0f / B_);
    const float varA = s2a * (1.0f / B_) - meanA * meanA;
    const float varB = s2b * (1.0f / B_) - meanB * meanB;
    const float rstdA = rsqrtf(varA + 1e-5f);
    const float rstdB = rsqrtf(varB + 1e-5f);
    const float gA = gamma[v0], beA = beta[v0];
    const float gB = gamma[v1], beB = beta[v1];

    float exs[4];
#pragma unroll
    for (int i = 0; i < 4; ++i) {
        const int b = bg * 4 + i;
        const size_t row = (size_t)b * V_;
        const float vm0 = VM[row + v0] + 1e-13f;
        const float vm1 = VM[row + v1] + 1e-13f;
        const float y0 = gA * (accA[i] - meanA) * rstdA + beA;
        const float y1 = gB * (accB[i] - meanB) * rstdB + beB;
        z[row + v0] = y0 + logf(vm0);
        z[row + v1] = y1 + logf(vm1);
        exs[i] = vm0 * expf(y0) + vm1 * expf(y1);
    }
#pragma unroll
    for (int i = 0; i < 4; ++i)
        atomicAdd(&pex[bg * 4 + i], exs[i]);
    __syncthreads();
    if (tid < B_) atomicAdd(&partial[tid], pex[tid]);
}

// ---------------- Kernel 4: out = z - log(partial[b])
__global__ __launch_bounds__(256) void k_final(const float* __restrict__ z,
                                               const float* __restrict__ partial,
                                               float* __restrict__ out) {
    const int idx = blockIdx.x * 256 + threadIdx.x;
    const int b = idx / (V_ / 4);
    const int v4 = idx % (V_ / 4);
    const float lse = logf(partial[b]);
    const float4 x = reinterpret_cast<const float4*>(z + (size_t)b * V_)[v4];
    float4 o;
    o.x = x.x - lse; o.y = x.y - lse; o.z = x.z - lse; o.w = x.w - lse;
    reinterpret_cast<float4*>(out + (size_t)b * V_)[v4] = o;
}

extern "C" void kernel_launch(void* const* d_in, const int* in_sizes, int n_in,
                              void* d_out, int out_size, void* d_ws, size_t ws_size,
                              hipStream_t stream) {
    const int* trainS = (const int*)d_in[0];
    const int* trainQ = (const int*)d_in[1];
    const float* trainVM = (const float*)d_in[2];
    const float* trainPM = (const float*)d_in[3];
    const float* trainQM = (const float*)d_in[5];
    const float* A1 = (const float*)d_in[6];
    const float* A2 = (const float*)d_in[7];
    const float* A3 = (const float*)d_in[8];
    const float* A4 = (const float*)d_in[9];
    const float* Wm = (const float*)d_in[10];
    const float* bias = (const float*)d_in[11];
    const float* gamma = (const float*)d_in[12];
    const float* beta = (const float*)d_in[13];
    float* out = (float*)d_out;

    float* ws = (float*)d_ws;
    float* u_T = ws;                                 // E*B = 8192 (transposed)
    float* embA = ws + 8192;                         // 4*B*M*E = 3,276,800
    float* z = embA + 4 * (B_ * M_ * E_);            // B*V = 1,024,000
    float* partial = z + (size_t)B_ * V_;            // 32

    k_embed<<<B_ * M_, 256, 0, stream>>>(trainS, A1, A2, A3, A4, embA);
    k_hops<<<B_, 1024, 0, stream>>>(trainQ, trainQM, A1, embA, trainPM, u_T, partial);
    k_output<<<V_ / 64, 256, 0, stream>>>(u_T, Wm, bias, gamma, beta, trainVM, z, partial);
    k_final<<<(B_ * V_ / 4) / 256, 256, 0, stream>>>(z, partial, out);
}